// Round 3
// baseline (145.419 us; speedup 1.0000x reference)
//
#include <hip/hip_runtime.h>
#include <hip/hip_bf16.h>

// Problem constants
#define B_    64
#define S_    512
#define W_    256
#define D_    768
#define NN    96    // 32 attrs * 3 classes

typedef __attribute__((ext_vector_type(8))) short bfrag;   // 8 bf16 (16 B)
typedef __attribute__((ext_vector_type(4))) float f32x4;
typedef __attribute__((ext_vector_type(4))) short s16x4;   // 4 bf16 (8 B)

static __device__ __forceinline__ short f2bf(float f) {
  __hip_bfloat16 h = __float2bfloat16(f);
  return __builtin_bit_cast(short, h);
}
static __device__ __forceinline__ s16x4 pack4(f32x4 v) {
  s16x4 r;
  r[0] = f2bf(v[0]); r[1] = f2bf(v[1]); r[2] = f2bf(v[2]); r[3] = f2bf(v[3]);
  return r;
}

// Kernel 0: pack cls_w [96][768] fp32 -> bf16 fragment-major in d_ws.
// Tile (nt 0..5, kk 0..23): 64 lanes x 16 B contiguous (1 KB/tile, 144 KB total).
// Lane l of tile supplies B[n = nt*16 + (l&15)][k = kk*32 + (l>>4)*8 + e].
__global__ void pack_b_kernel(const float* __restrict__ cw, short* __restrict__ pb) {
  const int t    = blockIdx.x * 256 + threadIdx.x;  // 0..9215
  const int lane = t & 63;
  const int tile = t >> 6;                          // nt*24 + kk
  const int kk   = tile % 24;
  const int nt   = tile / 24;
  const int n    = nt * 16 + (lane & 15);
  const int k    = kk * 32 + (lane >> 4) * 8;
  const float* src = cw + (size_t)n * D_ + k;
  f32x4 lo = *(const f32x4*)src;
  f32x4 hi = *(const f32x4*)(src + 4);
  s16x4* dst = (s16x4*)(pb + (size_t)t * 8);
  dst[0] = pack4(lo);
  dst[1] = pack4(hi);
}

// Main: block = one b, 32 w-rows x all 96 cols; 768 threads = 12 waves.
// Phase 1: stage whole gathered A tile (32x768) to LDS as bf16 (8 dwordx4
//          gathers per thread, back-to-back -> deep MLP), XOR-swizzled rows.
// Phase 2 (after ONE barrier): 24 x {ds_read_b128 A-frag, coalesced dwordx4
//          B-frag from packed L2-hot buffer, MFMA}, 2 accumulators.
__global__ __launch_bounds__(768, 6) void ner_kernel(
    const float* __restrict__ seq, const int* __restrict__ widx,
    const short* __restrict__ pb, const float* __restrict__ cb,
    float* __restrict__ out)
{
  __shared__ union {
    short a[32 * D_];    // 48 KB: A tile bf16, 1536 B/row, swizzled
    float o[32 * 100];   // epilogue staging
  } u;

  const int tid = threadIdx.x;
  const int blk = blockIdx.x;
  const int b   = blk >> 3;            // 8 blocks per batch element
  const int w0  = (blk & 7) << 5;      // 32 w-rows per block

  // ---- Phase 1: A staging. thread t covers rows {4p + t/192}, float4 col t%192
  const int col4  = tid % 192;
  const int rbase = tid / 192;         // 0..3
  const float* rowp[8];
  #pragma unroll
  for (int p = 0; p < 8; ++p) {
    const int r    = p * 4 + rbase;
    const int sidx = widx[b * W_ + w0 + r];
    rowp[p] = seq + ((size_t)b * S_ + sidx) * D_ + col4 * 4;
  }
  f32x4 va[8];
  #pragma unroll
  for (int p = 0; p < 8; ++p) va[p] = *(const f32x4*)rowp[p];   // 8 loads in flight
  char* const la = (char*)u.a;
  #pragma unroll
  for (int p = 0; p < 8; ++p) {
    const int r = p * 4 + rbase;
    *(s16x4*)(la + r * 1536 + ((col4 * 8) ^ ((r & 7) << 4))) = pack4(va[p]);
  }
  __syncthreads();

  // ---- Phase 2: compute
  const int lane = tid & 63;
  const int wv   = tid >> 6;           // 0..11
  const int mt   = wv & 1;
  const int nt   = wv >> 1;            // 0..5
  const int r16  = lane & 15;
  const int g    = lane >> 4;
  const int am   = mt * 16 + r16;      // A LDS row for this lane

  const short* bp = pb + ((size_t)(nt * 24) * 64 + lane) * 8;

  f32x4 acc0 = {0.f,0.f,0.f,0.f}, acc1 = {0.f,0.f,0.f,0.f};
  #pragma unroll 4
  for (int kk = 0; kk < 24; ++kk) {
    bfrag af = *(const bfrag*)(la + am * 1536 + ((kk * 64 + g * 16) ^ ((am & 7) << 4)));
    bfrag bf = *(const bfrag*)(bp + (size_t)kk * 512);   // 512 shorts = 1 KB tile stride
    if (kk & 1) acc1 = __builtin_amdgcn_mfma_f32_16x16x32_bf16(af, bf, acc1, 0, 0, 0);
    else        acc0 = __builtin_amdgcn_mfma_f32_16x16x32_bf16(af, bf, acc0, 0, 0, 0);
  }
  const f32x4 acc = acc0 + acc1;

  __syncthreads();     // LDS -> epilogue staging
  {
    // C/D layout: reg j of lane l -> D[(l>>4)*4 + j][l&15]
    const int n     = nt * 16 + r16;
    const float bias = cb[n];
    const int row0  = mt * 16 + g * 4;
    #pragma unroll
    for (int j = 0; j < 4; ++j)
      u.o[(row0 + j) * 100 + n] = acc[j] + bias;
  }
  __syncthreads();
  {
    // Coalesced stores: per attribute a, 32 rows x 3 = 96 contiguous floats.
    const int a  = tid / 24;           // 0..31
    const int e0 = (tid % 24) * 4;     // 0..92
    float vv[4];
    #pragma unroll
    for (int q = 0; q < 4; ++q) {
      const int e = e0 + q;
      vv[q] = u.o[(e / 3) * 100 + a * 3 + (e - (e / 3) * 3)];
    }
    float* op = out + ((size_t)(a * B_ + b) * W_ + w0) * 3 + e0;
    *(float4*)op = make_float4(vv[0], vv[1], vv[2], vv[3]);
  }
}

extern "C" void kernel_launch(void* const* d_in, const int* in_sizes, int n_in,
                              void* d_out, int out_size, void* d_ws, size_t ws_size,
                              hipStream_t stream) {
  const float* seq  = (const float*)d_in[0];   // [64, 512, 768] fp32
  const int*   widx = (const int*)d_in[1];     // [64, 256] int32
  const float* cw   = (const float*)d_in[2];   // [32, 3, 768] fp32
  const float* cb   = (const float*)d_in[3];   // [32, 3] fp32
  float* out  = (float*)d_out;                 // [32, 64, 256, 3] fp32
  short* pb   = (short*)d_ws;                  // 96*768 bf16 = 144 KB packed B

  pack_b_kernel<<<36, 256, 0, stream>>>(cw, pb);            // 9216 threads
  ner_kernel<<<B_ * (W_ / 32), 768, 0, stream>>>(seq, widx, pb, cb, out);
}